// Round 6
// baseline (79.104 us; speedup 1.0000x reference)
//
#include <hip/hip_runtime.h>
#include <hip/hip_fp16.h>

#define D 50
#define HIDDEN 32
#define NPW 16   // nodes per wave in node_proj

// ---------------------------------------------------------------------------
// Kernel 1: per-node projections -> fp16 table P[n][64]
//   P[n][j]    = sum_k z[n][k] * W1[k][j]      + b1[j]   (cols 0..31, src half)
//   P[n][32+j] = sum_k z[n][k] * W1[50+k][j]             (cols 32..63, dst half)
//
// No LDS. Lane c owns output column c; its 50 W1 values live in registers
// (launch_bounds(256,2) -> 256 VGPR budget). The node index is forced
// wave-uniform with readfirstlane so the z-row reads become SCALAR loads
// (s_load_dwordx8/16 batches on the SMEM pipe) -- no LDS traffic, no per-lane
// address math, FMAs consume the scalar operand directly.
// Store: lanes pair via shfl_xor, even lanes write packed __half2.
// ---------------------------------------------------------------------------
__global__ __launch_bounds__(256, 2) void node_proj_kernel(
        const float* __restrict__ z,
        const float* __restrict__ W1,
        const float* __restrict__ b1,
        __half2* __restrict__ P2,      // P viewed as half2[n_nodes][32]
        int n_nodes) {
    const int lane = threadIdx.x & 63;
    const int wid0 = (blockIdx.x * blockDim.x + threadIdx.x) >> 6;
    const int wid  = __builtin_amdgcn_readfirstlane(wid0);   // wave-uniform

    int n0 = wid * NPW;
    if (n0 >= n_nodes) return;
    int nend = n0 + NPW;
    if (nend > n_nodes) nend = n_nodes;

    const int j    = lane & 31;
    const int half = lane >> 5;

    // Per-lane W1 column in registers (coalesced: 128B row per k).
    float Breg[D];
    const float* wcol = W1 + (size_t)(half * D) * HIDDEN + j;
#pragma unroll
    for (int k = 0; k < D; ++k) Breg[k] = wcol[(size_t)k * HIDDEN];

    const float bias = half ? 0.0f : b1[j];

    for (int n = n0; n < nend; ++n) {
        const float2* zr = (const float2*)(z + (size_t)n * D);  // scalar addr
        float acc = bias;
#pragma unroll
        for (int q = 0; q < D / 2; ++q) {
            float2 zq = zr[q];               // wave-uniform -> s_load batches
            acc = fmaf(zq.x, Breg[2 * q],     acc);
            acc = fmaf(zq.y, Breg[2 * q + 1], acc);
        }
        float nb2 = __shfl_xor(acc, 1);
        if ((lane & 1) == 0) {
            P2[(size_t)n * 32 + (lane >> 1)] = __floats2half2_rn(acc, nb2);
        }
    }
}

// ---------------------------------------------------------------------------
// Kernel 2: per-edge fused add + relu + dot(W2) + b2.
// 4-lane group handles TWO edges (2x memory parallelism: 4 independent 16B
// gathers in flight per thread before any dependency). Lane r handles hidden
// units [8r, 8r+8); lanes 0..3 read consecutive 16B -> one 64B segment per
// edge-side. Group-sum via shfl_xor(1,2); lane 0 writes float2.
// ---------------------------------------------------------------------------
__device__ __forceinline__ float dot8(uint4 ua, uint4 ub, float4 w0, float4 w1,
                                      float init) {
    float2 a0 = __half22float2(*(const __half2*)&ua.x);
    float2 a1 = __half22float2(*(const __half2*)&ua.y);
    float2 a2 = __half22float2(*(const __half2*)&ua.z);
    float2 a3 = __half22float2(*(const __half2*)&ua.w);
    float2 b0 = __half22float2(*(const __half2*)&ub.x);
    float2 b1 = __half22float2(*(const __half2*)&ub.y);
    float2 b2 = __half22float2(*(const __half2*)&ub.z);
    float2 b3 = __half22float2(*(const __half2*)&ub.w);
    float acc = init;
    acc = fmaf(fmaxf(a0.x + b0.x, 0.0f), w0.x, acc);
    acc = fmaf(fmaxf(a0.y + b0.y, 0.0f), w0.y, acc);
    acc = fmaf(fmaxf(a1.x + b1.x, 0.0f), w0.z, acc);
    acc = fmaf(fmaxf(a1.y + b1.y, 0.0f), w0.w, acc);
    acc = fmaf(fmaxf(a2.x + b2.x, 0.0f), w1.x, acc);
    acc = fmaf(fmaxf(a2.y + b2.y, 0.0f), w1.y, acc);
    acc = fmaf(fmaxf(a3.x + b3.x, 0.0f), w1.z, acc);
    acc = fmaf(fmaxf(a3.y + b3.y, 0.0f), w1.w, acc);
    return acc;
}

__global__ __launch_bounds__(256) void edge_mlp_kernel(
        const int* __restrict__ eidx,
        const __half* __restrict__ P,
        const float* __restrict__ W2,
        const float* __restrict__ b2,
        float* __restrict__ out,
        int n_edges) {
    int t = blockIdx.x * blockDim.x + threadIdx.x;
    int g = t >> 2;
    int r = t & 3;
    int e0 = g * 2;
    if (e0 >= n_edges) return;
    bool two = (e0 + 1 < n_edges);

    int s0 = eidx[e0];
    int d0 = eidx[n_edges + e0];
    int s1 = two ? eidx[e0 + 1] : s0;
    int d1 = two ? eidx[n_edges + e0 + 1] : d0;

    // 4 independent gathers in flight.
    uint4 ua0 = *(const uint4*)(P + (size_t)s0 * 64 + r * 8);
    uint4 ub0 = *(const uint4*)(P + (size_t)d0 * 64 + 32 + r * 8);
    uint4 ua1 = *(const uint4*)(P + (size_t)s1 * 64 + r * 8);
    uint4 ub1 = *(const uint4*)(P + (size_t)d1 * 64 + 32 + r * 8);

    float4 w0 = *(const float4*)(W2 + r * 8);
    float4 w1 = *(const float4*)(W2 + r * 8 + 4);
    float init = (r == 0) ? b2[0] : 0.0f;

    float acc0 = dot8(ua0, ub0, w0, w1, init);
    float acc1 = dot8(ua1, ub1, w0, w1, init);

    acc0 += __shfl_xor(acc0, 1);
    acc0 += __shfl_xor(acc0, 2);
    acc1 += __shfl_xor(acc1, 1);
    acc1 += __shfl_xor(acc1, 2);

    if (r == 0) {
        if (two) {
            *(float2*)(out + e0) = make_float2(acc0, acc1);  // e0 even -> 8B aligned
        } else {
            out[e0] = acc0;
        }
    }
}

// ---------------------------------------------------------------------------
// Fallback (ws too small): direct per-edge full MLP. Slow but correct.
// ---------------------------------------------------------------------------
__global__ void edge_direct_kernel(const float* __restrict__ z,
                                   const int* __restrict__ eidx,
                                   const float* __restrict__ W1,
                                   const float* __restrict__ b1,
                                   const float* __restrict__ W2,
                                   const float* __restrict__ b2,
                                   float* __restrict__ out,
                                   int n_edges) {
    int e = blockIdx.x * blockDim.x + threadIdx.x;
    if (e >= n_edges) return;
    int s = eidx[e];
    int d = eidx[n_edges + e];
    const float* zs = z + (size_t)s * D;
    const float* zd = z + (size_t)d * D;
    float acc = b2[0];
    for (int j = 0; j < HIDDEN; ++j) {
        float h = b1[j];
        for (int k = 0; k < D; ++k) {
            h = fmaf(zs[k], W1[(size_t)k * HIDDEN + j], h);
            h = fmaf(zd[k], W1[(size_t)(D + k) * HIDDEN + j], h);
        }
        acc = fmaf(fmaxf(h, 0.0f), W2[j], acc);
    }
    out[e] = acc;
}

extern "C" void kernel_launch(void* const* d_in, const int* in_sizes, int n_in,
                              void* d_out, int out_size, void* d_ws, size_t ws_size,
                              hipStream_t stream) {
    const float* z    = (const float*)d_in[0];
    const int*   eidx = (const int*)d_in[1];
    const float* W1   = (const float*)d_in[2];
    const float* b1   = (const float*)d_in[3];
    const float* W2   = (const float*)d_in[4];
    const float* b2   = (const float*)d_in[5];
    float*       out  = (float*)d_out;

    const int n_nodes = in_sizes[0] / D;          // 100000
    const int n_edges = in_sizes[1] / 2;          // 2000000

    const size_t p_bytes = (size_t)n_nodes * 64 * sizeof(__half);

    if (p_bytes <= ws_size) {
        __half* P = (__half*)d_ws;

        // Kernel 1: one wave per NPW nodes, scalar z path.
        int n_waves = (n_nodes + NPW - 1) / NPW;
        int blocks1 = (n_waves * 64 + 255) / 256;
        node_proj_kernel<<<blocks1, 256, 0, stream>>>(z, W1, b1, (__half2*)P,
                                                      n_nodes);

        // Kernel 2: 4 threads per 2 edges.
        long long groups = ((long long)n_edges + 1) / 2;
        long long total2 = groups * 4;
        int blocks2 = (int)((total2 + 255) / 256);
        edge_mlp_kernel<<<blocks2, 256, 0, stream>>>(eidx, P, W2, b2, out, n_edges);
    } else {
        int blocks = (n_edges + 255) / 256;
        edge_direct_kernel<<<blocks, 256, 0, stream>>>(z, eidx, W1, b1, W2, b2,
                                                       out, n_edges);
    }
}